// Round 1
// 247.496 us; speedup vs baseline: 1.1312x; 1.1312x over previous
//
#include <hip/hip_runtime.h>
#include <hip/hip_bf16.h>

// Problem constants
#define KCODES 2048
#define DIM 256
#define TLEN 2048
#define NB 16
#define NROWS (NB * TLEN)          // 32768 rows (b*t)
#define NELEM (NB * DIM * TLEN)    // 8388608 elements of x / quant
#define LOSS_OFF NELEM
#define IDX_OFF (NELEM + 2)

// Approx filter margin (see R8: ~50-sigma safety for single hi*hi sweep).
#define MARGIN 3e-3f

// ws layout (bytes) — total 35.1 MB
#define OFF_XSQ   0ull                       // 131072
#define OFF_ESQ   131072ull                  // 8192
#define OFF_KEYS  139264ull                  // 262144
#define OFF_BSUM  401408ull                  // 131072
#define OFF_XHI   532480ull                  // 16777216
#define OFF_EHI   17309696ull                // 1048576
#define OFF_LMIN  18358272ull                // 8388608
#define OFF_MASK  26746880ull                // 8388608
#define WS_NEED   35135488ull

typedef __bf16 bf16x8 __attribute__((ext_vector_type(8)));
typedef float  f32x4  __attribute__((ext_vector_type(4)));

__device__ __forceinline__ float sq_rn(float v) { return __fmul_rn(v, v); }

// ---- x_sq: numpy pairwise sum (8-acc/128-block) — bit-exact vs np
__global__ __launch_bounds__(256) void xsq_kernel(const float* __restrict__ x,
                                                  float* __restrict__ xsq) {
    int m = blockIdx.x * 256 + threadIdx.x;
    int b = m >> 11, t = m & (TLEN - 1);
    const float* p = x + (size_t)b * DIM * TLEN + t;
    float h[2];
#pragma unroll
    for (int half = 0; half < 2; ++half) {
        int c0 = half * 128;
        float r[8];
#pragma unroll
        for (int j = 0; j < 8; ++j) r[j] = sq_rn(p[(size_t)(c0 + j) * TLEN]);
        for (int i = 8; i < 128; i += 8) {
#pragma unroll
            for (int j = 0; j < 8; ++j)
                r[j] = __fadd_rn(r[j], sq_rn(p[(size_t)(c0 + i + j) * TLEN]));
        }
        h[half] = __fadd_rn(__fadd_rn(__fadd_rn(r[0], r[1]), __fadd_rn(r[2], r[3])),
                            __fadd_rn(__fadd_rn(r[4], r[5]), __fadd_rn(r[6], r[7])));
    }
    xsq[m] = __fadd_rn(h[0], h[1]);
}

__global__ __launch_bounds__(256) void esq_kernel(const float* __restrict__ cb,
                                                  float* __restrict__ esq) {
    int k = blockIdx.x * 256 + threadIdx.x;
    const float* p = cb + (size_t)k * DIM;
    float h[2];
#pragma unroll
    for (int half = 0; half < 2; ++half) {
        int c0 = half * 128;
        float r[8];
#pragma unroll
        for (int j = 0; j < 8; ++j) r[j] = sq_rn(p[c0 + j]);
        for (int i = 8; i < 128; i += 8) {
#pragma unroll
            for (int j = 0; j < 8; ++j)
                r[j] = __fadd_rn(r[j], sq_rn(p[c0 + i + j]));
        }
        h[half] = __fadd_rn(__fadd_rn(__fadd_rn(r[0], r[1]), __fadd_rn(r[2], r[3])),
                            __fadd_rn(__fadd_rn(r[4], r[5]), __fadd_rn(r[6], r[7])));
    }
    esq[k] = __fadd_rn(h[0], h[1]);
}

// ---- x (layout [c][t] fp32) -> Xhi [m][k] bf16 (transpose + round)
__global__ __launch_bounds__(256) void split_x_kernel(const float* __restrict__ x,
                                                      __hip_bfloat16* __restrict__ Xhi) {
    __shared__ float tb[32][72];
    int blk = blockIdx.x;
    int tt = blk & 31, cc = (blk >> 5) & 7, b = blk >> 8;
    int c0 = cc << 5, t0 = tt << 6;
    int tid = threadIdx.x;
    {
        int c_l = tid >> 3, t8 = (tid & 7) << 3;
        const float* src = x + (size_t)b * DIM * TLEN + (size_t)(c0 + c_l) * TLEN + t0 + t8;
        float4 v0 = *reinterpret_cast<const float4*>(src);
        float4 v1 = *reinterpret_cast<const float4*>(src + 4);
        tb[c_l][t8 + 0] = v0.x; tb[c_l][t8 + 1] = v0.y; tb[c_l][t8 + 2] = v0.z; tb[c_l][t8 + 3] = v0.w;
        tb[c_l][t8 + 4] = v1.x; tb[c_l][t8 + 5] = v1.y; tb[c_l][t8 + 6] = v1.z; tb[c_l][t8 + 7] = v1.w;
    }
    __syncthreads();
    {
        int cp = tid & 3, m_l = tid >> 2;
        size_t m = (size_t)b * TLEN + t0 + m_l;
        alignas(16) __hip_bfloat16 h8[8];
#pragma unroll
        for (int j = 0; j < 8; ++j)
            h8[j] = __float2bfloat16(tb[(cp << 3) + j][m_l]);
        *reinterpret_cast<int4*>(Xhi + m * DIM + c0 + (cp << 3)) = *reinterpret_cast<int4*>(h8);
    }
}

// ---- codebook [n][k] fp32 -> Ehi [n][k] bf16
__global__ __launch_bounds__(256) void split_e_kernel(const float* __restrict__ cb,
                                                      __hip_bfloat16* __restrict__ Ehi) {
    int i4 = (blockIdx.x * 256 + threadIdx.x) << 2;
    float4 v = *reinterpret_cast<const float4*>(cb + i4);
    alignas(8) __hip_bfloat16 h4[4];
    h4[0] = __float2bfloat16(v.x); h4[1] = __float2bfloat16(v.y);
    h4[2] = __float2bfloat16(v.z); h4[3] = __float2bfloat16(v.w);
    *reinterpret_cast<int2*>(Ehi + i4) = *reinterpret_cast<int2*>(h4);
}

// ---- Phase A (rewritten): m97-style global_load_lds staging (BK=64, linear
// LDS + XOR-swizzle via pre-swizzled global source), swapped-operand MFMA so
// each lane owns 16 codes per x-row -> in-register min + 2-shfl reduce.
// Stored per-tile value is min(esq - 2*acc) = (approx d2) - xsq[m]; the
// row-constant xsq cancels in every comparison recheck performs, so the
// candidate-superset logic is unchanged (recheck switched to float compares
// because this value can be negative).
__global__ __launch_bounds__(256, 4) void mfma_dist_kernel(const __hip_bfloat16* __restrict__ Xhi,
                                                           const __hip_bfloat16* __restrict__ Ehi,
                                                           const float* __restrict__ esq,
                                                           unsigned long long* __restrict__ lmin,
                                                           unsigned long long* __restrict__ lmask) {
    __shared__ __hip_bfloat16 Ah[128 * 64];   // 16KB, x rows, swizzled layout
    __shared__ __hip_bfloat16 Bh[128 * 64];   // 16KB, codebook rows, swizzled

    int blk = blockIdx.x;
    int nt = blk & 15, mt = blk >> 4;
    int m0 = mt << 7, n0 = nt << 7;
    int tid = threadIdx.x;
    int w = tid >> 6, lane = tid & 63;
    int q = lane >> 4, c = lane & 15;
    int mhalf = w >> 1, nhalf = w & 1;

    // staging: wave w fills rows [w*32, w*32+32) of each 128x64 tile in 4
    // chunks of 8 rows. LDS dest is LINEAR (global_load_lds requirement);
    // the st-style XOR swizzle (byte ^= (row&7)<<4) is applied by swizzling
    // the per-lane GLOBAL source column instead.
    int srow = lane >> 3;                      // 0..7 within chunk
    int scol = ((lane & 7) ^ srow) << 3;       // pre-swizzled source col (elems)
    const __hip_bfloat16* gA = Xhi + (size_t)(m0 + (w << 5) + srow) * DIM + scol;
    const __hip_bfloat16* gB = Ehi + (size_t)(n0 + (w << 5) + srow) * DIM + scol;

    f32x4 acc[4][4];   // [ci (code subtile)][mi (x-row subtile)]
#pragma unroll
    for (int ci = 0; ci < 4; ++ci)
#pragma unroll
        for (int mi = 0; mi < 4; ++mi) acc[ci][mi] = (f32x4){0.f, 0.f, 0.f, 0.f};

    const char* AhB = reinterpret_cast<const char*>(Ah);
    const char* BhB = reinterpret_cast<const char*>(Bh);
    int swzc = (c & 7) << 4;                   // read-side XOR (row&7)<<4 == (c&7)<<4

    for (int kk = 0; kk < DIM; kk += 64) {
#pragma unroll
        for (int j = 0; j < 4; ++j)
            __builtin_amdgcn_global_load_lds(
                (const __attribute__((address_space(1))) unsigned int*)(gA + (size_t)(j << 3) * DIM + kk),
                (__attribute__((address_space(3))) unsigned int*)(&Ah[((w << 2) + j) << 9]),
                16, 0, 0);
#pragma unroll
        for (int j = 0; j < 4; ++j)
            __builtin_amdgcn_global_load_lds(
                (const __attribute__((address_space(1))) unsigned int*)(gB + (size_t)(j << 3) * DIM + kk),
                (__attribute__((address_space(3))) unsigned int*)(&Bh[((w << 2) + j) << 9]),
                16, 0, 0);
        __syncthreads();
#pragma unroll
        for (int kh = 0; kh < 2; ++kh) {
            int swz = ((kh << 6) | (q << 4)) ^ swzc;
            bf16x8 xf[4], cf[4];
#pragma unroll
            for (int mi = 0; mi < 4; ++mi) {
                int row = (mhalf << 6) + (mi << 4) + c;
                xf[mi] = *reinterpret_cast<const bf16x8*>(AhB + (row << 7) + swz);
            }
#pragma unroll
            for (int ci = 0; ci < 4; ++ci) {
                int row = (nhalf << 6) + (ci << 4) + c;
                cf[ci] = *reinterpret_cast<const bf16x8*>(BhB + (row << 7) + swz);
            }
#pragma unroll
            for (int ci = 0; ci < 4; ++ci)
#pragma unroll
                for (int mi = 0; mi < 4; ++mi)
                    acc[ci][mi] = __builtin_amdgcn_mfma_f32_16x16x32_bf16(cf[ci], xf[mi], acc[ci][mi], 0, 0, 0);
        }
        __syncthreads();
    }

    // Epilogue: D[code][xrow] -> lane (q,c) holds x-rows {mi*16+c} and codes
    // {ci*16 + q*4 + reg}. Per row: in-register 16-way fmin tree + xor-16/32
    // shfl across the 4 q-lanes; mask bits likewise. lmin low 32 bits unused.
    int tb = (nt << 1) | nhalf;
    float ev[16];
#pragma unroll
    for (int ci = 0; ci < 4; ++ci)
#pragma unroll
        for (int reg = 0; reg < 4; ++reg)
            ev[ci * 4 + reg] = esq[n0 + (nhalf << 6) + ci * 16 + (q << 2) + reg];

#pragma unroll
    for (int mi = 0; mi < 4; ++mi) {
        float s[16];
#pragma unroll
        for (int ci = 0; ci < 4; ++ci)
#pragma unroll
            for (int reg = 0; reg < 4; ++reg)
                s[ci * 4 + reg] = fmaf(-2.0f, acc[ci][mi][reg], ev[ci * 4 + reg]);
        float a0 = fminf(fminf(s[0], s[1]), fminf(s[2], s[3]));
        float a1 = fminf(fminf(s[4], s[5]), fminf(s[6], s[7]));
        float a2 = fminf(fminf(s[8], s[9]), fminf(s[10], s[11]));
        float a3 = fminf(fminf(s[12], s[13]), fminf(s[14], s[15]));
        float bd = fminf(fminf(a0, a1), fminf(a2, a3));
        bd = fminf(bd, __shfl_xor(bd, 16, 64));
        bd = fminf(bd, __shfl_xor(bd, 32, 64));
        float thr = bd + MARGIN;
        unsigned long long bits = 0;
#pragma unroll
        for (int ci = 0; ci < 4; ++ci)
#pragma unroll
            for (int reg = 0; reg < 4; ++reg)
                if (s[ci * 4 + reg] <= thr)
                    bits |= 1ULL << (ci * 16 + (q << 2) + reg);
        bits |= (unsigned long long)__shfl_xor((long long)bits, 16, 64);
        bits |= (unsigned long long)__shfl_xor((long long)bits, 32, 64);
        if (q == 0) {
            int m = m0 + (mhalf << 6) + (mi << 4) + c;
            lmin[(size_t)m * 32 + tb] = ((unsigned long long)__float_as_uint(bd) << 32);
            lmask[(size_t)m * 32 + tb] = bits;
        }
    }
}

// ---- Phase B: 32 rows/block, coalesced x staging, 8-lane group per row.
// lmin values are now (d2_approx - xsq[m]) and may be negative -> float
// min/compares (xsq cancels row-wise, so candidate sets are identical).
// Final d2 recomputed exactly in fp32 -> bit-exact result unchanged.
#define CCAP 40
__global__ __launch_bounds__(256) void recheck_kernel(const float* __restrict__ x,
                                                      const float* __restrict__ cb,
                                                      const float* __restrict__ xsq,
                                                      const float* __restrict__ esq,
                                                      const unsigned long long* __restrict__ lmin,
                                                      const unsigned long long* __restrict__ lmask,
                                                      unsigned long long* __restrict__ keys) {
    __shared__ float xT[DIM * 33];     // [c][tl] stride 33: staging 2-way (free), dot broadcast
    __shared__ int clist[32][CCAP];
    __shared__ int ccnt[32];

    int tid = threadIdx.x;
    int blk = blockIdx.x;               // 1024 blocks
    int b = blk >> 6, t0 = (blk & 63) << 5;
    const float* xb = x + (size_t)b * DIM * TLEN + t0;

    if (tid < 32) ccnt[tid] = 0;
    {   // coalesced staging: 8 c-rows x 32 t per iter
        int tl = tid & 31, c8 = tid >> 5;
        for (int cc = 0; cc < 32; ++cc) {
            int c = (cc << 3) + c8;
            xT[c * 33 + tl] = xb[(size_t)c * TLEN + tl];
        }
    }
    __syncthreads();

    int g = tid >> 3, l3 = tid & 7;     // group g handles row t0+g
    int m = (b << 11) + t0 + g;

    // row min over 32 tiles (4 per lane, then width-8 shfl reduce)
    float rmv4[4];
    float rm = 3.4e38f;
#pragma unroll
    for (int j = 0; j < 4; ++j) {
        rmv4[j] = __uint_as_float((unsigned)(lmin[(size_t)m * 32 + l3 * 4 + j] >> 32));
        rm = fminf(rm, rmv4[j]);
    }
    for (int off = 1; off < 8; off <<= 1)
        rm = fminf(rm, __shfl_xor(rm, off, 8));
    float thr = rm + MARGIN;

    // collect candidates from qualifying tiles
#pragma unroll
    for (int j = 0; j < 4; ++j) {
        if (rmv4[j] <= thr) {
            int tb = l3 * 4 + j;
            unsigned long long msk = lmask[(size_t)m * 32 + tb];
            while (msk) {
                int bit = __ffsll((long long)msk) - 1;
                msk &= msk - 1;
                int pos = atomicAdd(&ccnt[g], 1);
                if (pos < CCAP) clist[g][pos] = tb * 64 + bit;
            }
        }
    }
    __syncthreads();

    int cnt = ccnt[g]; if (cnt > CCAP) cnt = CCAP;
    float xs = xsq[m];
    float bd = 3.4e38f; int bi = 0x7fffffff;
    for (int j = l3; j < cnt; j += 8) {
        int n = clist[g][j];
        const float* crow = cb + (size_t)n * DIM;
        float d = 0.f;
        for (int k = 0; k < DIM; k += 4) {     // ascending-k fmaf chain == np mm
            float4 cv = *reinterpret_cast<const float4*>(crow + k);
            d = fmaf(xT[(k + 0) * 33 + g], cv.x, d);
            d = fmaf(xT[(k + 1) * 33 + g], cv.y, d);
            d = fmaf(xT[(k + 2) * 33 + g], cv.z, d);
            d = fmaf(xT[(k + 3) * 33 + g], cv.w, d);
        }
        float d2 = __fadd_rn(__fadd_rn(xs, -2.0f * d), esq[n]);   // exact ref rounding
        if (d2 < bd || (d2 == bd && n < bi)) { bd = d2; bi = n; }
    }
    for (int off = 1; off < 8; off <<= 1) {
        float od = __shfl_xor(bd, off, 8);
        int   oi = __shfl_xor(bi, off, 8);
        if (od < bd || (od == bd && oi < bi)) { bd = od; bi = oi; }
    }
    if (l3 == 0)
        keys[m] = ((unsigned long long)__float_as_uint(bd) << 32) | (unsigned)(bi & 2047);
}

// ======== fallback path (R5): used only if ws_size is too small ========
__global__ __launch_bounds__(256) void init_keys_kernel(unsigned long long* __restrict__ keys) {
    keys[blockIdx.x * 256 + threadIdx.x] = ~0ULL;
}

__global__ __launch_bounds__(256, 4) void dist_kernel(const float* __restrict__ x,
                                                      const float* __restrict__ cb,
                                                      const float* __restrict__ xsq,
                                                      const float* __restrict__ esq,
                                                      unsigned long long* __restrict__ keys) {
    __shared__ float As[16][128];
    __shared__ float Bs[16][132];
    int blk = blockIdx.x;
    int nt = blk & 15, mt = blk >> 4;
    int m0 = mt << 7;
    int b = m0 >> 11, t0 = m0 & (TLEN - 1);
    int n0 = nt << 7;
    int tid = threadIdx.x;
    int tm = tid >> 4, tn = tid & 15;
    const float* xbase = x + (size_t)b * DIM * TLEN + t0;
    float acc[8][8] = {};
    for (int kk = 0; kk < DIM; kk += 16) {
#pragma unroll
        for (int h = 0; h < 2; ++h) {
            int qq = tid + (h << 8);
            int k = qq >> 5, mq = (qq & 31) << 2;
            float4 v = *reinterpret_cast<const float4*>(xbase + (size_t)(kk + k) * TLEN + mq);
            *reinterpret_cast<float4*>(&As[k][mq]) = v;
        }
#pragma unroll
        for (int h = 0; h < 2; ++h) {
            int qq = tid + (h << 8);
            int nr = qq >> 2, kc = (qq & 3) << 2;
            float4 v = *reinterpret_cast<const float4*>(cb + (size_t)(n0 + nr) * DIM + kk + kc);
            Bs[kc + 0][nr] = v.x; Bs[kc + 1][nr] = v.y;
            Bs[kc + 2][nr] = v.z; Bs[kc + 3][nr] = v.w;
        }
        __syncthreads();
#pragma unroll
        for (int k = 0; k < 16; ++k) {
            float4 a0 = *reinterpret_cast<const float4*>(&As[k][tm << 2]);
            float4 a1 = *reinterpret_cast<const float4*>(&As[k][64 + (tm << 2)]);
            float4 b0 = *reinterpret_cast<const float4*>(&Bs[k][tn << 2]);
            float4 b1 = *reinterpret_cast<const float4*>(&Bs[k][64 + (tn << 2)]);
            float am[8] = {a0.x, a0.y, a0.z, a0.w, a1.x, a1.y, a1.z, a1.w};
            float bn[8] = {b0.x, b0.y, b0.z, b0.w, b1.x, b1.y, b1.z, b1.w};
#pragma unroll
            for (int mi = 0; mi < 8; ++mi)
#pragma unroll
                for (int ni = 0; ni < 8; ++ni)
                    acc[mi][ni] = fmaf(am[mi], bn[ni], acc[mi][ni]);
        }
        __syncthreads();
    }
    int cn[8]; float es[8];
#pragma unroll
    for (int ni = 0; ni < 8; ++ni) {
        cn[ni] = n0 + ((ni < 4) ? (tn << 2) + ni : 60 + (tn << 2) + ni);
        es[ni] = esq[cn[ni]];
    }
#pragma unroll
    for (int mi = 0; mi < 8; ++mi) {
        int m = m0 + ((mi < 4) ? (tm << 2) + mi : 60 + (tm << 2) + mi);
        float xs = xsq[m];
        float bd = 3.4e38f;
        int bi = 0x7fffffff;
#pragma unroll
        for (int ni = 0; ni < 8; ++ni) {
            float d2 = __fadd_rn(__fadd_rn(xs, -2.0f * acc[mi][ni]), es[ni]);
            if (d2 < bd) { bd = d2; bi = cn[ni]; }
        }
        for (int off = 1; off < 16; off <<= 1) {
            float od = __shfl_xor(bd, off, 16);
            int oi = __shfl_xor(bi, off, 16);
            if (od < bd || (od == bd && oi < bi)) { bd = od; bi = oi; }
        }
        if (tn == 0) {
            unsigned long long key =
                ((unsigned long long)__float_as_uint(bd) << 32) | (unsigned)(bi & 2047);
            atomicMin(&keys[m], key);
        }
    }
}
// ======== end fallback ========

// ---- gather + STE output + idx + per-block loss sums
__global__ __launch_bounds__(256) void gather_kernel(const float* __restrict__ x,
                                                     const float* __restrict__ cb,
                                                     const unsigned long long* __restrict__ keys,
                                                     float* __restrict__ out,
                                                     float* __restrict__ bsum) {
    int e = blockIdx.x * 256 + threadIdx.x;
    int t = e & (TLEN - 1);
    int c = (e >> 11) & (DIM - 1);
    int b = e >> 19;
    int m = (b << 11) | t;
    unsigned idx = (unsigned)(keys[m]) & 2047u;
    float q = cb[(size_t)idx * DIM + c];
    float xv = x[e];
    float diff = __fsub_rn(q, xv);
    float o = __fadd_rn(xv, diff);
    out[e] = o;
    if (c == 0) out[(size_t)IDX_OFF + m] = (float)idx;

    float s = __fmul_rn(diff, diff);
    for (int off = 32; off > 0; off >>= 1) s += __shfl_down(s, off, 64);
    __shared__ float wsum[4];
    int lane = threadIdx.x & 63, wid = threadIdx.x >> 6;
    if (lane == 0) wsum[wid] = s;
    __syncthreads();
    if (threadIdx.x == 0)
        bsum[blockIdx.x] = ((wsum[0] + wsum[1]) + (wsum[2] + wsum[3]));
}

__global__ __launch_bounds__(1024) void finalize_kernel(const float* __restrict__ bsum,
                                                        float* __restrict__ out) {
    double s = 0.0;
    for (int i = threadIdx.x; i < 32768; i += 1024) s += (double)bsum[i];
    for (int off = 32; off > 0; off >>= 1) s += __shfl_down(s, off, 64);
    __shared__ double wsum[16];
    int lane = threadIdx.x & 63, wid = threadIdx.x >> 6;
    if (lane == 0) wsum[wid] = s;
    __syncthreads();
    if (threadIdx.x == 0) {
        double total = 0.0;
        for (int ww = 0; ww < 16; ++ww) total += wsum[ww];
        float mean = (float)(total / (double)NELEM);
        out[LOSS_OFF] = mean;
        out[LOSS_OFF + 1] = 0.25f * mean;
    }
}

extern "C" void kernel_launch(void* const* d_in, const int* in_sizes, int n_in,
                              void* d_out, int out_size, void* d_ws, size_t ws_size,
                              hipStream_t stream) {
    const float* x  = (const float*)d_in[0];
    const float* cb = (const float*)d_in[1];
    float* out = (float*)d_out;
    char* ws = (char*)d_ws;
    float* xsq = (float*)(ws + OFF_XSQ);
    float* esq = (float*)(ws + OFF_ESQ);
    unsigned long long* keys = (unsigned long long*)(ws + OFF_KEYS);
    float* bsum = (float*)(ws + OFF_BSUM);

    xsq_kernel<<<NROWS / 256, 256, 0, stream>>>(x, xsq);
    esq_kernel<<<KCODES / 256, 256, 0, stream>>>(cb, esq);

    if (ws_size >= WS_NEED) {
        __hip_bfloat16* Xhi = (__hip_bfloat16*)(ws + OFF_XHI);
        __hip_bfloat16* Ehi = (__hip_bfloat16*)(ws + OFF_EHI);
        unsigned long long* lmin  = (unsigned long long*)(ws + OFF_LMIN);
        unsigned long long* lmask = (unsigned long long*)(ws + OFF_MASK);
        split_x_kernel<<<NB * 8 * 32, 256, 0, stream>>>(x, Xhi);
        split_e_kernel<<<(KCODES * DIM) / 1024, 256, 0, stream>>>(cb, Ehi);
        mfma_dist_kernel<<<(NROWS / 128) * (KCODES / 128), 256, 0, stream>>>(
            Xhi, Ehi, esq, lmin, lmask);
        recheck_kernel<<<NROWS / 32, 256, 0, stream>>>(x, cb, xsq, esq, lmin, lmask, keys);
    } else {
        init_keys_kernel<<<NROWS / 256, 256, 0, stream>>>(keys);
        dist_kernel<<<(NROWS / 128) * (KCODES / 128), 256, 0, stream>>>(x, cb, xsq, esq, keys);
    }
    gather_kernel<<<NELEM / 256, 256, 0, stream>>>(x, cb, keys, out, bsum);
    finalize_kernel<<<1, 1024, 0, stream>>>(bsum, out);
}